// Round 5
// baseline (496.912 us; speedup 1.0000x reference)
//
#include <hip/hip_runtime.h>
#include <hip/hip_bf16.h>
#include <math.h>

#define N_NODES 20000
#define N_EDGES 320000
#define F_IN    127
#define ETOT    (N_EDGES + N_NODES)

typedef __attribute__((ext_vector_type(8))) short short8;
typedef __attribute__((ext_vector_type(4))) float f32x4;

__device__ inline unsigned short f2bf(float f) {
  union { float f; unsigned int u; } v; v.f = f;
  unsigned int u = v.u;
  unsigned int r = (u + 0x7fffu + ((u >> 16) & 1u)) >> 16;
  return (unsigned short)r;
}
__device__ inline unsigned int pack2bf(float lo, float hi) {
  return (unsigned int)f2bf(lo) | ((unsigned int)f2bf(hi) << 16);
}
__device__ inline float bf2f(unsigned short b) {
  union { unsigned int u; float f; } v; v.u = ((unsigned int)b) << 16;
  return v.f;
}
__device__ inline float bflo(unsigned int v) {
  union { unsigned int u; float f; } x; x.u = v << 16; return x.f;
}
__device__ inline float bfhi(unsigned int v) {
  union { unsigned int u; float f; } x; x.u = v & 0xffff0000u; return x.f;
}

// ---------------- CSR build ----------------
__global__ void k_init(int* __restrict__ counts, float* __restrict__ stats) {
  int i = blockIdx.x * blockDim.x + threadIdx.x;
  if (i < N_NODES) counts[i] = 1;   // self loop pre-counted
  if (i < 2048) stats[i] = 0.f;
}

__global__ void k_hist(const int* __restrict__ ei, int* __restrict__ counts) {
  int e = blockIdx.x * blockDim.x + threadIdx.x;
  if (e < N_EDGES) atomicAdd(&counts[ei[N_EDGES + e]], 1);
}

// scan + self-loop placement + write-cursor init (merged)
__global__ __launch_bounds__(1024) void k_scan(const int* __restrict__ counts,
                                               int* __restrict__ row_start,
                                               int* __restrict__ wcur,
                                               int* __restrict__ srcs) {
  __shared__ int part[1024];
  const int per = (N_NODES + 1023) / 1024;
  int t = threadIdx.x;
  int base = t * per;
  int s = 0;
  for (int i = 0; i < per; ++i) {
    int idx = base + i;
    if (idx < N_NODES) s += counts[idx];
  }
  part[t] = s;
  __syncthreads();
  for (int off = 1; off < 1024; off <<= 1) {
    int v = (t >= off) ? part[t - off] : 0;
    __syncthreads();
    part[t] += v;
    __syncthreads();
  }
  int run = part[t] - s;
  for (int i = 0; i < per; ++i) {
    int idx = base + i;
    if (idx < N_NODES) {
      row_start[idx] = run;
      srcs[run] = idx;          // self loop at slot 0 of each row
      wcur[idx] = run + 1;
      run += counts[idx];
    }
  }
  if (t == 1023) row_start[N_NODES] = part[1023];
}

__global__ void k_scatter(const int* __restrict__ ei, int* __restrict__ wcur,
                          int* __restrict__ srcs) {
  int e = blockIdx.x * blockDim.x + threadIdx.x;
  if (e < N_EDGES) {
    int s = ei[e], d = ei[N_EDGES + e];
    int p = atomicAdd(&wcur[d], 1);
    srcs[p] = s;
  }
}

// ---------------- input concat + weight cast/transpose (merged) ----------------
__global__ void k_prep(const float* __restrict__ X, const float* __restrict__ pos,
                       unsigned short* __restrict__ xbf,
                       const float* __restrict__ W1, const float* __restrict__ W2,
                       const float* __restrict__ oW,
                       unsigned short* __restrict__ W1t, unsigned short* __restrict__ W2t,
                       unsigned short* __restrict__ oWt) {
  int i = blockIdx.x * blockDim.x + threadIdx.x;
  if (i < N_NODES * 128) { int n = i >> 7, k = i & 127; xbf[i] = f2bf((k < F_IN) ? X[n * F_IN + k] : pos[n]); }
  if (i < 128 * 512) { int r = i >> 9, c = i & 511; W1t[c * 128 + r] = f2bf(W1[i]); }
  if (i < 512 * 512) { int r = i >> 9, c = i & 511; W2t[c * 512 + r] = f2bf(W2[i]); }
  if (i < 512 * 256) { int r = i >> 8, c = i & 255; oWt[c * 512 + r] = f2bf(oW[i]); }
}

// ---------------- bf16 MFMA GEMM: C = A[M,K] @ Bt[Nc,K]^T (+bias) ----------------
// 128x128 tile, 256 thr (4 waves, 2x2), each wave 64x64 = 4x4 MFMA 16x16x32.
__global__ __launch_bounds__(256) void k_mgemm(
    const unsigned short* __restrict__ A, const unsigned short* __restrict__ Bt,
    const float* __restrict__ bias, float* __restrict__ Cf,
    unsigned short* __restrict__ Cbf, int M, int Nc, int K)
{
  __shared__ unsigned short As[128 * 32];
  __shared__ unsigned short Bs[128 * 32];
  int t = threadIdx.x;
  int w = t >> 6, l = t & 63;
  int wr = w >> 1, wc = w & 1;
  int lane15 = l & 15, kq = l >> 4;
  int m0 = blockIdx.y * 128, n0 = blockIdx.x * 128;
  f32x4 acc[4][4] = {};

  int cA = 2 * w;
  int rowA0 = 16 * cA + (l >> 2);
  int koff = (l & 3) * 8;

  for (int k0 = 0; k0 < K; k0 += 32) {
    __syncthreads();
#pragma unroll
    for (int cc = 0; cc < 2; ++cc) {
      int c = cA + cc;
      int row = rowA0 + 16 * cc;
      const unsigned short* g = A + (size_t)min(m0 + row, M - 1) * K + k0 + koff;
      __builtin_amdgcn_global_load_lds(
          (const __attribute__((address_space(1))) unsigned int*)g,
          (__attribute__((address_space(3))) unsigned int*)&As[c * 512], 16, 0, 0);
      const unsigned short* gb = Bt + (size_t)(n0 + row) * K + k0 + koff;
      __builtin_amdgcn_global_load_lds(
          (const __attribute__((address_space(1))) unsigned int*)gb,
          (__attribute__((address_space(3))) unsigned int*)&Bs[c * 512], 16, 0, 0);
    }
    __syncthreads();
    short8 a[4], b[4];
#pragma unroll
    for (int i = 0; i < 4; ++i)
      a[i] = *(const short8*)&As[(wr * 64 + i * 16 + lane15) * 32 + kq * 8];
#pragma unroll
    for (int j = 0; j < 4; ++j)
      b[j] = *(const short8*)&Bs[(wc * 64 + j * 16 + lane15) * 32 + kq * 8];
#pragma unroll
    for (int i = 0; i < 4; ++i)
#pragma unroll
      for (int j = 0; j < 4; ++j)
        acc[i][j] = __builtin_amdgcn_mfma_f32_16x16x32_bf16(a[i], b[j], acc[i][j], 0, 0, 0);
  }
  // epilogue: C/D layout col=lane&15, row=(lane>>4)*4+reg
#pragma unroll
  for (int i = 0; i < 4; ++i) {
#pragma unroll
    for (int j = 0; j < 4; ++j) {
      int col = n0 + wc * 64 + j * 16 + lane15;
      float bv = bias ? bias[col] : 0.f;
#pragma unroll
      for (int r = 0; r < 4; ++r) {
        int row = m0 + wr * 64 + i * 16 + kq * 4 + r;
        if (row < M) {
          float val = acc[i][j][r] + bv;
          if (Cbf) Cbf[(size_t)row * Nc + col] = f2bf(val);
          else     Cf[(size_t)row * Nc + col] = val;
        }
      }
    }
  }
}

// ---------------- attention logit vectors al_s/al_d [N,4], bf16 input ----------------
__global__ __launch_bounds__(256) void k_al(
    const unsigned short* __restrict__ xlbf, const float* __restrict__ a_src,
    const float* __restrict__ a_dst, float* __restrict__ al_s, float* __restrict__ al_d)
{
  int n = blockIdx.x, t = threadIdx.x;
  int h = t >> 6, l = t & 63;
  int c0 = h * 128 + 2 * l;
  unsigned int v = *(const unsigned int*)&xlbf[(size_t)n * 512 + c0];
  float v0 = bflo(v), v1 = bfhi(v);
  float ps = v0 * a_src[c0] + v1 * a_src[c0 + 1];
  float pd = v0 * a_dst[c0] + v1 * a_dst[c0 + 1];
#pragma unroll
  for (int off = 32; off; off >>= 1) { ps += __shfl_down(ps, off); pd += __shfl_down(pd, off); }
  if (l == 0) { al_s[n * 4 + h] = ps; al_d[n * 4 + h] = pd; }
}

// ---------------- GAT aggregate: wave-per-node, 16B/lane, unroll-8 batches ----------------
// Block 256 = 4 waves; wave w owns node blockIdx.x*4+w. Lane l: channels 8l..8l+7
// (head = l>>4). Softmax per-head in 16-lane subgroups. Output bf16 (+bias).
__global__ __launch_bounds__(256) void k_agg(
    const unsigned short* __restrict__ xlbf, const float* __restrict__ al_s,
    const float* __restrict__ al_d, const int* __restrict__ row_start,
    const int* __restrict__ srcs, const float* __restrict__ bias,
    unsigned short* __restrict__ outbf)
{
  int w = threadIdx.x >> 6, l = threadIdx.x & 63;
  int n = blockIdx.x * 4 + w;
  if (n >= N_NODES) return;
  int h = l >> 4;          // head owning channels 8l..8l+7
  int g = l & 15;          // lane within head subgroup
  __shared__ float s_al[4][64][4];   // [wave][edge][head]
  __shared__ int   s_src[4][64];
  __shared__ float s_m[4][4], s_r[4][4];

  int rs = row_start[n];
  int deg = row_start[n + 1] - rs;
  float ald_h = al_d[n * 4 + h];

  // phase A: online softmax per head, 16-lane subgroup strided over edges
  float lm = -1e30f, ls = 0.f;
  for (int i = g; i < deg; i += 16) {
    int s = srcs[rs + i];
    float lg = al_s[s * 4 + h] + ald_h;
    lg = (lg >= 0.f) ? lg : 0.2f * lg;
    if (lg > lm) { ls = ls * __expf(lm - lg) + 1.f; lm = lg; }
    else         { ls += __expf(lg - lm); }
  }
#pragma unroll
  for (int off = 8; off; off >>= 1) {
    float om = __shfl_xor(lm, off);
    float os = __shfl_xor(ls, off);
    float M = fmaxf(lm, om);
    ls = ls * __expf(lm - M) + os * __expf(om - M);
    lm = M;
  }
  if (g == 0) {
    s_m[w][h] = lm;
    s_r[w][h] = 1.f / (ls + 1e-16f);
  }
  // wave-synchronous: LDS write->read within one wave is program-ordered

  float acc[8] = {};
  const unsigned short* xp = xlbf + 8 * l;
  float4 ad4 = *(const float4*)&al_d[n * 4];
  for (int c0 = 0; c0 < deg; c0 += 64) {
    int csz = min(64, deg - c0);
    int cpad = (csz + 7) & ~7;        // pad to 8 with alpha=0, src=n
    if (l < cpad) {
      bool valid = l < csz;
      int s = valid ? srcs[rs + c0 + l] : n;
      s_src[w][l] = s;
      if (valid) {
        float4 as4 = *(const float4*)&al_s[(size_t)s * 4];
        float lg0 = as4.x + ad4.x; lg0 = (lg0 >= 0.f) ? lg0 : 0.2f * lg0;
        float lg1 = as4.y + ad4.y; lg1 = (lg1 >= 0.f) ? lg1 : 0.2f * lg1;
        float lg2 = as4.z + ad4.z; lg2 = (lg2 >= 0.f) ? lg2 : 0.2f * lg2;
        float lg3 = as4.w + ad4.w; lg3 = (lg3 >= 0.f) ? lg3 : 0.2f * lg3;
        s_al[w][l][0] = __expf(lg0 - s_m[w][0]) * s_r[w][0];
        s_al[w][l][1] = __expf(lg1 - s_m[w][1]) * s_r[w][1];
        s_al[w][l][2] = __expf(lg2 - s_m[w][2]) * s_r[w][2];
        s_al[w][l][3] = __expf(lg3 - s_m[w][3]) * s_r[w][3];
      } else {
        s_al[w][l][0] = 0.f; s_al[w][l][1] = 0.f;
        s_al[w][l][2] = 0.f; s_al[w][l][3] = 0.f;
      }
    }
    for (int e = 0; e < cpad; e += 8) {
      float a[8]; int ss[8];
#pragma unroll
      for (int j = 0; j < 8; ++j) { a[j] = s_al[w][e + j][h]; ss[j] = s_src[w][e + j]; }
      uint4 v[8];
#pragma unroll
      for (int j = 0; j < 8; ++j) v[j] = *(const uint4*)(xp + (size_t)ss[j] * 512);
#pragma unroll
      for (int j = 0; j < 8; ++j) {
        acc[0] = fmaf(bflo(v[j].x), a[j], acc[0]);
        acc[1] = fmaf(bfhi(v[j].x), a[j], acc[1]);
        acc[2] = fmaf(bflo(v[j].y), a[j], acc[2]);
        acc[3] = fmaf(bfhi(v[j].y), a[j], acc[3]);
        acc[4] = fmaf(bflo(v[j].z), a[j], acc[4]);
        acc[5] = fmaf(bfhi(v[j].z), a[j], acc[5]);
        acc[6] = fmaf(bflo(v[j].w), a[j], acc[6]);
        acc[7] = fmaf(bfhi(v[j].w), a[j], acc[7]);
      }
    }
  }
  int c = 8 * l;
  float4 b0 = *(const float4*)&bias[c];
  float4 b1 = *(const float4*)&bias[c + 4];
  uint4 ov;
  ov.x = pack2bf(acc[0] + b0.x, acc[1] + b0.y);
  ov.y = pack2bf(acc[2] + b0.z, acc[3] + b0.w);
  ov.z = pack2bf(acc[4] + b1.x, acc[5] + b1.y);
  ov.w = pack2bf(acc[6] + b1.z, acc[7] + b1.w);
  *(uint4*)&outbf[(size_t)n * 512 + c] = ov;
}

// ---------------- column stats (sum, sumsq) over bf16 matrix ----------------
// 256 thr; thread t owns channels 2t, 2t+1. Blocks stride over row chunks.
#define STATS_ROWS 160
__global__ __launch_bounds__(256) void k_stats(const unsigned int* __restrict__ hbf2,
                                               float* __restrict__ sums) {
  int t = threadIdx.x;
  int r0 = blockIdx.x * STATS_ROWS;
  int r1 = min(r0 + STATS_ROWS, N_NODES);
  float s0 = 0.f, s1 = 0.f, q0 = 0.f, q1 = 0.f;
  for (int r = r0; r < r1; ++r) {
    unsigned int v = hbf2[(size_t)r * 256 + t];
    float v0 = bflo(v), v1 = bfhi(v);
    s0 += v0; q0 = fmaf(v0, v0, q0);
    s1 += v1; q1 = fmaf(v1, v1, q1);
  }
  atomicAdd(&sums[2 * t], s0);
  atomicAdd(&sums[2 * t + 1], s1);
  atomicAdd(&sums[512 + 2 * t], q0);
  atomicAdd(&sums[512 + 2 * t + 1], q1);
}

// ---------------- BN + LeakyReLU(0.01): bf16 -> bf16, channel pairs ----------------
__global__ void k_bn_act(const unsigned int* __restrict__ in2, unsigned int* __restrict__ out2,
                         const float* __restrict__ stats,
                         const float* __restrict__ g, const float* __restrict__ b) {
  int i = blockIdx.x * blockDim.x + threadIdx.x;
  if (i >= N_NODES * 256) return;
  int t = i & 255;
  int c = 2 * t;
  const float invN = 1.f / N_NODES;
  float mu0 = stats[c] * invN, mu1 = stats[c + 1] * invN;
  float sc0 = rsqrtf(stats[512 + c] * invN - mu0 * mu0 + 1e-5f) * g[c];
  float sc1 = rsqrtf(stats[512 + c + 1] * invN - mu1 * mu1 + 1e-5f) * g[c + 1];
  unsigned int v = in2[i];
  float y0 = (bflo(v) - mu0) * sc0 + b[c];
  float y1 = (bfhi(v) - mu1) * sc1 + b[c + 1];
  y0 = (y0 >= 0.f) ? y0 : 0.01f * y0;
  y1 = (y1 >= 0.f) ? y1 : 0.01f * y1;
  out2[i] = pack2bf(y0, y1);
}

// BN + act + residual (bf16 h1) -> bf16
__global__ void k_bn_act_res(const unsigned int* __restrict__ in2, const unsigned int* __restrict__ prev2,
                             unsigned int* __restrict__ out2,
                             const float* __restrict__ stats,
                             const float* __restrict__ g, const float* __restrict__ b) {
  int i = blockIdx.x * blockDim.x + threadIdx.x;
  if (i >= N_NODES * 256) return;
  int t = i & 255;
  int c = 2 * t;
  const float invN = 1.f / N_NODES;
  float mu0 = stats[c] * invN, mu1 = stats[c + 1] * invN;
  float sc0 = rsqrtf(stats[512 + c] * invN - mu0 * mu0 + 1e-5f) * g[c];
  float sc1 = rsqrtf(stats[512 + c + 1] * invN - mu1 * mu1 + 1e-5f) * g[c + 1];
  unsigned int v = in2[i];
  unsigned int pv = prev2[i];
  float y0 = (bflo(v) - mu0) * sc0 + b[c];
  float y1 = (bfhi(v) - mu1) * sc1 + b[c + 1];
  y0 = (y0 >= 0.f) ? y0 : 0.01f * y0;
  y1 = (y1 >= 0.f) ? y1 : 0.01f * y1;
  out2[i] = pack2bf(y0 + bflo(pv), y1 + bfhi(pv));
}

extern "C" void kernel_launch(void* const* d_in, const int* in_sizes, int n_in,
                              void* d_out, int out_size, void* d_ws, size_t ws_size,
                              hipStream_t stream) {
  const float* X      = (const float*)d_in[0];
  const int*   ei     = (const int*)d_in[1];
  const float* pos    = (const float*)d_in[3];
  const float* W1     = (const float*)d_in[4];
  const float* a_src1 = (const float*)d_in[5];
  const float* a_dst1 = (const float*)d_in[6];
  const float* b1     = (const float*)d_in[7];
  const float* W2     = (const float*)d_in[8];
  const float* a_src2 = (const float*)d_in[9];
  const float* a_dst2 = (const float*)d_in[10];
  const float* b2     = (const float*)d_in[11];
  const float* bn1_g  = (const float*)d_in[12];
  const float* bn1_b  = (const float*)d_in[13];
  const float* bn2_g  = (const float*)d_in[14];
  const float* bn2_b  = (const float*)d_in[15];
  const float* out_W  = (const float*)d_in[18];
  const float* out_b  = (const float*)d_in[19];
  float* out = (float*)d_out;

  float* ws = (float*)d_ws;
  size_t o = 0;
  float* alS   = ws + o; o += (size_t)N_NODES * 4;
  float* alD   = ws + o; o += (size_t)N_NODES * 4;
  float* stats = ws + o; o += 2048;
  unsigned short* aggbf = (unsigned short*)(ws + o); o += (size_t)N_NODES * 256; // 20.5 MB (pre-BN, both layers)
  unsigned short* xlbf  = (unsigned short*)(ws + o); o += (size_t)N_NODES * 256; // GEMM out (both layers)
  unsigned short* xbf   = (unsigned short*)(ws + o); o += (size_t)N_NODES * 64;  // input bf16
  unsigned short* hbf   = (unsigned short*)(ws + o); o += (size_t)N_NODES * 256; // h1 bf16 (GEMM2 in + residual)
  unsigned short* h2bf  = (unsigned short*)(ws + o); o += (size_t)N_NODES * 256; // h2 bf16 (out-proj in)
  unsigned short* W1t   = (unsigned short*)(ws + o); o += 128 * 512 / 2;
  unsigned short* W2t   = (unsigned short*)(ws + o); o += 512 * 512 / 2;
  unsigned short* oWt   = (unsigned short*)(ws + o); o += 512 * 256 / 2;
  int* ip = (int*)(ws + o);
  int* counts    = ip; ip += N_NODES;
  int* row_start = ip; ip += N_NODES + 1;
  int* wcur      = ip; ip += N_NODES;
  int* srcs      = ip; ip += ETOT;

  // CSR by dst (self loops included) + input prep
  k_init   <<<(N_NODES + 255) / 256, 256, 0, stream>>>(counts, stats);
  k_hist   <<<(N_EDGES + 255) / 256, 256, 0, stream>>>(ei, counts);
  k_scan   <<<1, 1024, 0, stream>>>(counts, row_start, wcur, srcs);
  k_scatter<<<(N_EDGES + 255) / 256, 256, 0, stream>>>(ei, wcur, srcs);
  k_prep   <<<(N_NODES * 128 + 255) / 256, 256, 0, stream>>>(X, pos, xbf, W1, W2, out_W, W1t, W2t, oWt);

  // ---- layer 1 ----
  { dim3 g(512 / 128, (N_NODES + 127) / 128);
    k_mgemm<<<g, 256, 0, stream>>>(xbf, W1t, nullptr, nullptr, xlbf, N_NODES, 512, 128); }
  k_al  <<<N_NODES, 256, 0, stream>>>(xlbf, a_src1, a_dst1, alS, alD);
  k_agg <<<(N_NODES + 3) / 4, 256, 0, stream>>>(xlbf, alS, alD, row_start, srcs, b1, aggbf);
  k_stats<<<(N_NODES + STATS_ROWS - 1) / STATS_ROWS, 256, 0, stream>>>((const unsigned int*)aggbf, stats);
  k_bn_act<<<(N_NODES * 256 + 255) / 256, 256, 0, stream>>>((const unsigned int*)aggbf, (unsigned int*)hbf, stats, bn1_g, bn1_b);
  // ---- layer 2 ----
  { dim3 g(512 / 128, (N_NODES + 127) / 128);
    k_mgemm<<<g, 256, 0, stream>>>(hbf, W2t, nullptr, nullptr, xlbf, N_NODES, 512, 512); }
  k_al  <<<N_NODES, 256, 0, stream>>>(xlbf, a_src2, a_dst2, alS, alD);
  k_agg <<<(N_NODES + 3) / 4, 256, 0, stream>>>(xlbf, alS, alD, row_start, srcs, b2, aggbf);
  k_stats<<<(N_NODES + STATS_ROWS - 1) / STATS_ROWS, 256, 0, stream>>>((const unsigned int*)aggbf, stats + 1024);
  k_bn_act_res<<<(N_NODES * 256 + 255) / 256, 256, 0, stream>>>((const unsigned int*)aggbf, (const unsigned int*)hbf, (unsigned int*)h2bf, stats + 1024, bn2_g, bn2_b);
  // ---- output projection ----
  { dim3 g(256 / 128, (N_NODES + 127) / 128);
    k_mgemm<<<g, 256, 0, stream>>>(h2bf, oWt, out_b, out, nullptr, N_NODES, 256, 512); }
}

// Round 6
// 483.660 us; speedup vs baseline: 1.0274x; 1.0274x over previous
//
#include <hip/hip_runtime.h>
#include <hip/hip_bf16.h>
#include <math.h>

#define N_NODES 20000
#define N_EDGES 320000
#define F_IN    127
#define ETOT    (N_EDGES + N_NODES)

typedef __attribute__((ext_vector_type(8))) short short8;
typedef __attribute__((ext_vector_type(4))) float f32x4;

__device__ inline unsigned short f2bf(float f) {
  union { float f; unsigned int u; } v; v.f = f;
  unsigned int u = v.u;
  unsigned int r = (u + 0x7fffu + ((u >> 16) & 1u)) >> 16;
  return (unsigned short)r;
}
__device__ inline unsigned int pack2bf(float lo, float hi) {
  return (unsigned int)f2bf(lo) | ((unsigned int)f2bf(hi) << 16);
}
__device__ inline float bf2f(unsigned short b) {
  union { unsigned int u; float f; } v; v.u = ((unsigned int)b) << 16;
  return v.f;
}
__device__ inline float bflo(unsigned int v) {
  union { unsigned int u; float f; } x; x.u = v << 16; return x.f;
}
__device__ inline float bfhi(unsigned int v) {
  union { unsigned int u; float f; } x; x.u = v & 0xffff0000u; return x.f;
}

// ---------------- setup: zero counters/stats/al + concat input + cast weights ----------------
__global__ void k_setup(int* __restrict__ counts, float* __restrict__ stats,
                        float* __restrict__ alZ,   // 4 x N_NODES*4 floats (alS1,alD1,alS2,alD2)
                        const float* __restrict__ X, const float* __restrict__ pos,
                        unsigned short* __restrict__ xbf,
                        const float* __restrict__ W1, const float* __restrict__ W2,
                        const float* __restrict__ oW,
                        unsigned short* __restrict__ W1t, unsigned short* __restrict__ W2t,
                        unsigned short* __restrict__ oWt) {
  int i = blockIdx.x * blockDim.x + threadIdx.x;
  if (i < N_NODES) counts[i] = 1;   // self loop pre-counted
  if (i < 2048) stats[i] = 0.f;
  if (i < N_NODES * 16) alZ[i] = 0.f;
  if (i < N_NODES * 128) { int n = i >> 7, k = i & 127; xbf[i] = f2bf((k < F_IN) ? X[n * F_IN + k] : pos[n]); }
  if (i < 128 * 512) { int r = i >> 9, c = i & 511; W1t[c * 128 + r] = f2bf(W1[i]); }
  if (i < 512 * 512) { int r = i >> 9, c = i & 511; W2t[c * 512 + r] = f2bf(W2[i]); }
  if (i < 512 * 256) { int r = i >> 8, c = i & 255; oWt[c * 512 + r] = f2bf(oW[i]); }
}

__global__ void k_hist(const int* __restrict__ ei, int* __restrict__ counts) {
  int e = blockIdx.x * blockDim.x + threadIdx.x;
  if (e < N_EDGES) atomicAdd(&counts[ei[N_EDGES + e]], 1);
}

// scan + self-loop placement + write-cursor init (merged)
__global__ __launch_bounds__(1024) void k_scan(const int* __restrict__ counts,
                                               int* __restrict__ row_start,
                                               int* __restrict__ wcur,
                                               int* __restrict__ srcs) {
  __shared__ int part[1024];
  const int per = (N_NODES + 1023) / 1024;
  int t = threadIdx.x;
  int base = t * per;
  int s = 0;
  for (int i = 0; i < per; ++i) {
    int idx = base + i;
    if (idx < N_NODES) s += counts[idx];
  }
  part[t] = s;
  __syncthreads();
  for (int off = 1; off < 1024; off <<= 1) {
    int v = (t >= off) ? part[t - off] : 0;
    __syncthreads();
    part[t] += v;
    __syncthreads();
  }
  int run = part[t] - s;
  for (int i = 0; i < per; ++i) {
    int idx = base + i;
    if (idx < N_NODES) {
      row_start[idx] = run;
      srcs[run] = idx;          // self loop at slot 0 of each row
      wcur[idx] = run + 1;
      run += counts[idx];
    }
  }
  if (t == 1023) row_start[N_NODES] = part[1023];
}

__global__ void k_scatter(const int* __restrict__ ei, int* __restrict__ wcur,
                          int* __restrict__ srcs) {
  int e = blockIdx.x * blockDim.x + threadIdx.x;
  if (e < N_EDGES) {
    int s = ei[e], d = ei[N_EDGES + e];
    int p = atomicAdd(&wcur[d], 1);
    srcs[p] = s;
  }
}

// ---------------- bf16 MFMA GEMM: C = A[M,K] @ Bt[Nc,K]^T (+bias) ----------------
// 128x128 tile, 256 thr (4 waves, 2x2), each wave 64x64 = 4x4 MFMA 16x16x32.
// Optional fused attention-logit epilogue (asrc/adst non-null, Nc==512):
// column-block n0 is exactly head n0>>7; per-row partial dot -> atomicAdd.
__global__ __launch_bounds__(256) void k_mgemm(
    const unsigned short* __restrict__ A, const unsigned short* __restrict__ Bt,
    const float* __restrict__ bias, float* __restrict__ Cf,
    unsigned short* __restrict__ Cbf, int M, int Nc, int K,
    const float* __restrict__ asrc, const float* __restrict__ adst,
    float* __restrict__ alS, float* __restrict__ alD)
{
  __shared__ unsigned short As[128 * 32];
  __shared__ unsigned short Bs[128 * 32];
  int t = threadIdx.x;
  int w = t >> 6, l = t & 63;
  int wr = w >> 1, wc = w & 1;
  int lane15 = l & 15, kq = l >> 4;
  int m0 = blockIdx.y * 128, n0 = blockIdx.x * 128;
  f32x4 acc[4][4] = {};

  int cA = 2 * w;
  int rowA0 = 16 * cA + (l >> 2);
  int koff = (l & 3) * 8;

  for (int k0 = 0; k0 < K; k0 += 32) {
    __syncthreads();
#pragma unroll
    for (int cc = 0; cc < 2; ++cc) {
      int c = cA + cc;
      int row = rowA0 + 16 * cc;
      const unsigned short* g = A + (size_t)min(m0 + row, M - 1) * K + k0 + koff;
      __builtin_amdgcn_global_load_lds(
          (const __attribute__((address_space(1))) unsigned int*)g,
          (__attribute__((address_space(3))) unsigned int*)&As[c * 512], 16, 0, 0);
      const unsigned short* gb = Bt + (size_t)(n0 + row) * K + k0 + koff;
      __builtin_amdgcn_global_load_lds(
          (const __attribute__((address_space(1))) unsigned int*)gb,
          (__attribute__((address_space(3))) unsigned int*)&Bs[c * 512], 16, 0, 0);
    }
    __syncthreads();
    short8 a[4], b[4];
#pragma unroll
    for (int i = 0; i < 4; ++i)
      a[i] = *(const short8*)&As[(wr * 64 + i * 16 + lane15) * 32 + kq * 8];
#pragma unroll
    for (int j = 0; j < 4; ++j)
      b[j] = *(const short8*)&Bs[(wc * 64 + j * 16 + lane15) * 32 + kq * 8];
#pragma unroll
    for (int i = 0; i < 4; ++i)
#pragma unroll
      for (int j = 0; j < 4; ++j)
        acc[i][j] = __builtin_amdgcn_mfma_f32_16x16x32_bf16(a[i], b[j], acc[i][j], 0, 0, 0);
  }
  // epilogue: C/D layout col=lane&15, row=(lane>>4)*4+reg
#pragma unroll
  for (int i = 0; i < 4; ++i) {
#pragma unroll
    for (int j = 0; j < 4; ++j) {
      int col = n0 + wc * 64 + j * 16 + lane15;
      float bv = bias ? bias[col] : 0.f;
#pragma unroll
      for (int r = 0; r < 4; ++r) {
        int row = m0 + wr * 64 + i * 16 + kq * 4 + r;
        if (row < M) {
          float val = acc[i][j][r] + bv;
          if (Cbf) Cbf[(size_t)row * Nc + col] = f2bf(val);
          else     Cf[(size_t)row * Nc + col] = val;
        }
      }
    }
  }
  // fused attention-logit partials
  if (asrc) {
    int head = n0 >> 7;
    float as4[4], ad4[4];
#pragma unroll
    for (int j = 0; j < 4; ++j) {
      int col = n0 + wc * 64 + j * 16 + lane15;
      as4[j] = asrc[col]; ad4[j] = adst[col];
    }
#pragma unroll
    for (int i = 0; i < 4; ++i) {
#pragma unroll
      for (int r = 0; r < 4; ++r) {
        float ps = 0.f, pd = 0.f;
#pragma unroll
        for (int j = 0; j < 4; ++j) {
          ps = fmaf(acc[i][j][r], as4[j], ps);
          pd = fmaf(acc[i][j][r], ad4[j], pd);
        }
#pragma unroll
        for (int off = 1; off < 16; off <<= 1) {
          ps += __shfl_xor(ps, off);
          pd += __shfl_xor(pd, off);
        }
        int row = m0 + wr * 64 + i * 16 + kq * 4 + r;
        if (lane15 == 0 && row < M) {
          atomicAdd(&alS[row * 4 + head], ps);
          atomicAdd(&alD[row * 4 + head], pd);
        }
      }
    }
  }
}

// ---------------- GAT aggregate: wave-per-node, 16B/lane gathers ----------------
// Block 256 = 4 waves; wave w owns node blockIdx.x*4+w. Lane l: channels 8l..8l+7
// (head = l>>4). Softmax per-head in 16-lane subgroups. Output bf16 (+bias).
__global__ __launch_bounds__(256) void k_agg(
    const unsigned short* __restrict__ xlbf, const float* __restrict__ al_s,
    const float* __restrict__ al_d, const int* __restrict__ row_start,
    const int* __restrict__ srcs, const float* __restrict__ bias,
    unsigned short* __restrict__ outbf)
{
  int w = threadIdx.x >> 6, l = threadIdx.x & 63;
  int n = blockIdx.x * 4 + w;
  if (n >= N_NODES) return;
  int h = l >> 4;          // head owning channels 8l..8l+7
  int g = l & 15;          // lane within head subgroup
  __shared__ float s_al[4][64][4];   // [wave][edge][head]
  __shared__ int   s_src[4][64];
  __shared__ float s_m[4][4], s_r[4][4];

  int rs = row_start[n];
  int deg = row_start[n + 1] - rs;
  float ald_h = al_d[n * 4 + h];

  // phase A: online softmax per head, 16-lane subgroup strided over edges
  float lm = -1e30f, ls = 0.f;
  for (int i = g; i < deg; i += 16) {
    int s = srcs[rs + i];
    float lg = al_s[s * 4 + h] + ald_h;
    lg = (lg >= 0.f) ? lg : 0.2f * lg;
    if (lg > lm) { ls = ls * __expf(lm - lg) + 1.f; lm = lg; }
    else         { ls += __expf(lg - lm); }
  }
#pragma unroll
  for (int off = 8; off; off >>= 1) {
    float om = __shfl_xor(lm, off);
    float os = __shfl_xor(ls, off);
    float M = fmaxf(lm, om);
    ls = ls * __expf(lm - M) + os * __expf(om - M);
    lm = M;
  }
  if (g == 0) {
    s_m[w][h] = lm;
    s_r[w][h] = 1.f / (ls + 1e-16f);
  }
  // wave-synchronous: LDS write->read within one wave is program-ordered

  float acc[8] = {};
  const unsigned short* xp = xlbf + 8 * l;
  float4 ad4 = *(const float4*)&al_d[n * 4];
  for (int c0 = 0; c0 < deg; c0 += 64) {
    int csz = min(64, deg - c0);
    if (l < csz) {
      int s = srcs[rs + c0 + l];
      s_src[w][l] = s;
      float4 as4 = *(const float4*)&al_s[(size_t)s * 4];
      float lg0 = as4.x + ad4.x; lg0 = (lg0 >= 0.f) ? lg0 : 0.2f * lg0;
      float lg1 = as4.y + ad4.y; lg1 = (lg1 >= 0.f) ? lg1 : 0.2f * lg1;
      float lg2 = as4.z + ad4.z; lg2 = (lg2 >= 0.f) ? lg2 : 0.2f * lg2;
      float lg3 = as4.w + ad4.w; lg3 = (lg3 >= 0.f) ? lg3 : 0.2f * lg3;
      s_al[w][l][0] = __expf(lg0 - s_m[w][0]) * s_r[w][0];
      s_al[w][l][1] = __expf(lg1 - s_m[w][1]) * s_r[w][1];
      s_al[w][l][2] = __expf(lg2 - s_m[w][2]) * s_r[w][2];
      s_al[w][l][3] = __expf(lg3 - s_m[w][3]) * s_r[w][3];
    }
#pragma unroll 4
    for (int e = 0; e < csz; ++e) {
      float a = s_al[w][e][h];
      int s = s_src[w][e];
      uint4 v = *(const uint4*)(xp + (size_t)s * 512);
      acc[0] = fmaf(bflo(v.x), a, acc[0]);
      acc[1] = fmaf(bfhi(v.x), a, acc[1]);
      acc[2] = fmaf(bflo(v.y), a, acc[2]);
      acc[3] = fmaf(bfhi(v.y), a, acc[3]);
      acc[4] = fmaf(bflo(v.z), a, acc[4]);
      acc[5] = fmaf(bfhi(v.z), a, acc[5]);
      acc[6] = fmaf(bflo(v.w), a, acc[6]);
      acc[7] = fmaf(bfhi(v.w), a, acc[7]);
    }
  }
  int c = 8 * l;
  float4 b0 = *(const float4*)&bias[c];
  float4 b1 = *(const float4*)&bias[c + 4];
  uint4 ov;
  ov.x = pack2bf(acc[0] + b0.x, acc[1] + b0.y);
  ov.y = pack2bf(acc[2] + b0.z, acc[3] + b0.w);
  ov.z = pack2bf(acc[4] + b1.x, acc[5] + b1.y);
  ov.w = pack2bf(acc[6] + b1.z, acc[7] + b1.w);
  *(uint4*)&outbf[(size_t)n * 512 + c] = ov;
}

// ---------------- column stats (sum, sumsq) over bf16 matrix ----------------
#define STATS_ROWS 40
__global__ __launch_bounds__(256) void k_stats(const unsigned int* __restrict__ hbf2,
                                               float* __restrict__ sums) {
  int t = threadIdx.x;
  int r0 = blockIdx.x * STATS_ROWS;
  int r1 = min(r0 + STATS_ROWS, N_NODES);
  float s0 = 0.f, s1 = 0.f, q0 = 0.f, q1 = 0.f;
  for (int r = r0; r < r1; ++r) {
    unsigned int v = hbf2[(size_t)r * 256 + t];
    float v0 = bflo(v), v1 = bfhi(v);
    s0 += v0; q0 = fmaf(v0, v0, q0);
    s1 += v1; q1 = fmaf(v1, v1, q1);
  }
  atomicAdd(&sums[2 * t], s0);
  atomicAdd(&sums[2 * t + 1], s1);
  atomicAdd(&sums[512 + 2 * t], q0);
  atomicAdd(&sums[512 + 2 * t + 1], q1);
}

// ---------------- BN + LeakyReLU(0.01): bf16 -> bf16, channel pairs ----------------
__global__ void k_bn_act(const unsigned int* __restrict__ in2, unsigned int* __restrict__ out2,
                         const float* __restrict__ stats,
                         const float* __restrict__ g, const float* __restrict__ b) {
  int i = blockIdx.x * blockDim.x + threadIdx.x;
  if (i >= N_NODES * 256) return;
  int t = i & 255;
  int c = 2 * t;
  const float invN = 1.f / N_NODES;
  float mu0 = stats[c] * invN, mu1 = stats[c + 1] * invN;
  float sc0 = rsqrtf(stats[512 + c] * invN - mu0 * mu0 + 1e-5f) * g[c];
  float sc1 = rsqrtf(stats[512 + c + 1] * invN - mu1 * mu1 + 1e-5f) * g[c + 1];
  unsigned int v = in2[i];
  float y0 = (bflo(v) - mu0) * sc0 + b[c];
  float y1 = (bfhi(v) - mu1) * sc1 + b[c + 1];
  y0 = (y0 >= 0.f) ? y0 : 0.01f * y0;
  y1 = (y1 >= 0.f) ? y1 : 0.01f * y1;
  out2[i] = pack2bf(y0, y1);
}

// BN + act + residual (bf16 h1) -> bf16
__global__ void k_bn_act_res(const unsigned int* __restrict__ in2, const unsigned int* __restrict__ prev2,
                             unsigned int* __restrict__ out2,
                             const float* __restrict__ stats,
                             const float* __restrict__ g, const float* __restrict__ b) {
  int i = blockIdx.x * blockDim.x + threadIdx.x;
  if (i >= N_NODES * 256) return;
  int t = i & 255;
  int c = 2 * t;
  const float invN = 1.f / N_NODES;
  float mu0 = stats[c] * invN, mu1 = stats[c + 1] * invN;
  float sc0 = rsqrtf(stats[512 + c] * invN - mu0 * mu0 + 1e-5f) * g[c];
  float sc1 = rsqrtf(stats[512 + c + 1] * invN - mu1 * mu1 + 1e-5f) * g[c + 1];
  unsigned int v = in2[i];
  unsigned int pv = prev2[i];
  float y0 = (bflo(v) - mu0) * sc0 + b[c];
  float y1 = (bfhi(v) - mu1) * sc1 + b[c + 1];
  y0 = (y0 >= 0.f) ? y0 : 0.01f * y0;
  y1 = (y1 >= 0.f) ? y1 : 0.01f * y1;
  out2[i] = pack2bf(y0 + bflo(pv), y1 + bfhi(pv));
}

extern "C" void kernel_launch(void* const* d_in, const int* in_sizes, int n_in,
                              void* d_out, int out_size, void* d_ws, size_t ws_size,
                              hipStream_t stream) {
  const float* X      = (const float*)d_in[0];
  const int*   ei     = (const int*)d_in[1];
  const float* pos    = (const float*)d_in[3];
  const float* W1     = (const float*)d_in[4];
  const float* a_src1 = (const float*)d_in[5];
  const float* a_dst1 = (const float*)d_in[6];
  const float* b1     = (const float*)d_in[7];
  const float* W2     = (const float*)d_in[8];
  const float* a_src2 = (const float*)d_in[9];
  const float* a_dst2 = (const float*)d_in[10];
  const float* b2     = (const float*)d_in[11];
  const float* bn1_g  = (const float*)d_in[12];
  const float* bn1_b  = (const float*)d_in[13];
  const float* bn2_g  = (const float*)d_in[14];
  const float* bn2_b  = (const float*)d_in[15];
  const float* out_W  = (const float*)d_in[18];
  const float* out_b  = (const float*)d_in[19];
  float* out = (float*)d_out;

  float* ws = (float*)d_ws;
  size_t o = 0;
  float* alZ   = ws + o; o += (size_t)N_NODES * 16;    // alS1|alD1|alS2|alD2
  float* alS1  = alZ;
  float* alD1  = alZ + N_NODES * 4;
  float* alS2  = alZ + N_NODES * 8;
  float* alD2  = alZ + N_NODES * 12;
  float* stats = ws + o; o += 2048;
  unsigned short* aggbf = (unsigned short*)(ws + o); o += (size_t)N_NODES * 256; // pre-BN (both layers)
  unsigned short* xlbf  = (unsigned short*)(ws + o); o += (size_t)N_NODES * 256; // GEMM out (both layers)
  unsigned short* xbf   = (unsigned short*)(ws + o); o += (size_t)N_NODES * 64;  // input bf16
  unsigned short* hbf   = (unsigned short*)(ws + o); o += (size_t)N_NODES * 256; // h1 bf16 (GEMM2 in + residual)
  unsigned short* h2bf  = (unsigned short*)(ws + o); o += (size_t)N_NODES * 256; // h2 bf16 (out-proj in)
  unsigned short* W1t   = (unsigned short*)(ws + o); o += 128 * 512 / 2;
  unsigned short* W2t   = (unsigned short*)(ws + o); o += 512 * 512 / 2;
  unsigned short* oWt   = (unsigned short*)(ws + o); o += 512 * 256 / 2;
  int* ip = (int*)(ws + o);
  int* counts    = ip; ip += N_NODES;
  int* row_start = ip; ip += N_NODES + 1;
  int* wcur      = ip; ip += N_NODES;
  int* srcs      = ip; ip += ETOT;

  // setup (zero + concat + weight cast) and CSR build
  k_setup  <<<(N_NODES * 128 + 255) / 256, 256, 0, stream>>>(counts, stats, alZ, X, pos, xbf,
                                                             W1, W2, out_W, W1t, W2t, oWt);
  k_hist   <<<(N_EDGES + 255) / 256, 256, 0, stream>>>(ei, counts);
  k_scan   <<<1, 1024, 0, stream>>>(counts, row_start, wcur, srcs);
  k_scatter<<<(N_EDGES + 255) / 256, 256, 0, stream>>>(ei, wcur, srcs);

  // ---- layer 1 ----
  { dim3 g(512 / 128, (N_NODES + 127) / 128);
    k_mgemm<<<g, 256, 0, stream>>>(xbf, W1t, nullptr, nullptr, xlbf, N_NODES, 512, 128,
                                   a_src1, a_dst1, alS1, alD1); }
  k_agg <<<(N_NODES + 3) / 4, 256, 0, stream>>>(xlbf, alS1, alD1, row_start, srcs, b1, aggbf);
  k_stats<<<(N_NODES + STATS_ROWS - 1) / STATS_ROWS, 256, 0, stream>>>((const unsigned int*)aggbf, stats);
  k_bn_act<<<(N_NODES * 256 + 255) / 256, 256, 0, stream>>>((const unsigned int*)aggbf, (unsigned int*)hbf, stats, bn1_g, bn1_b);
  // ---- layer 2 ----
  { dim3 g(512 / 128, (N_NODES + 127) / 128);
    k_mgemm<<<g, 256, 0, stream>>>(hbf, W2t, nullptr, nullptr, xlbf, N_NODES, 512, 512,
                                   a_src2, a_dst2, alS2, alD2); }
  k_agg <<<(N_NODES + 3) / 4, 256, 0, stream>>>(xlbf, alS2, alD2, row_start, srcs, b2, aggbf);
  k_stats<<<(N_NODES + STATS_ROWS - 1) / STATS_ROWS, 256, 0, stream>>>((const unsigned int*)aggbf, stats + 1024);
  k_bn_act_res<<<(N_NODES * 256 + 255) / 256, 256, 0, stream>>>((const unsigned int*)aggbf, (const unsigned int*)hbf, (unsigned int*)h2bf, stats + 1024, bn2_g, bn2_b);
  // ---- output projection ----
  { dim3 g(256 / 128, (N_NODES + 127) / 128);
    k_mgemm<<<g, 256, 0, stream>>>(h2bf, oWt, out_b, out, nullptr, N_NODES, 256, 512,
                                   nullptr, nullptr, nullptr, nullptr); }
}